// Round 8
// baseline (108.295 us; speedup 1.0000x reference)
//
#include <hip/hip_runtime.h>

// Fast HW transcendentals (v_exp_f32 / v_log_f32 / v_rcp_f32), with fallbacks.
#if __has_builtin(__builtin_amdgcn_exp2f)
#define FAST_EXP2(x) __builtin_amdgcn_exp2f(x)
#else
#define FAST_EXP2(x) exp2f(x)
#endif
#if __has_builtin(__builtin_amdgcn_logf)
#define FAST_LOG2(x) __builtin_amdgcn_logf(x)
#else
#define FAST_LOG2(x) log2f(x)
#endif
#if __has_builtin(__builtin_amdgcn_rcpf)
#define FAST_RCP(x) __builtin_amdgcn_rcpf(x)
#else
#define FAST_RCP(x) (1.0f / (x))
#endif

#define LOG2E 1.44269504088896340736f

// Compiler-generated vector math ONLY (rounds 4-6 condemned inline-asm v_pk_*:
// VOP3P packed-fp32 modifier semantics did not match the ISA-text reading).
typedef float v2f __attribute__((ext_vector_type(2)));

__device__ __forceinline__ v2f v2fma(v2f a, v2f b, v2f c) {
    return __builtin_elementwise_fma(a, b, c);
}

// tanh on a pair; per-element math/order identical to rounds 1-3/7.
__device__ __forceinline__ v2f fast_tanh2(v2f v) {
    v2f t = v * (v2f)(2.0f * LOG2E);
    v2f e;
    e.x = FAST_EXP2(t.x);
    e.y = FAST_EXP2(t.y);
    v2f d = e + (v2f)(1.0f);
    v2f r;
    r.x = FAST_RCP(d.x);
    r.y = FAST_RCP(d.y);
    return v2fma((v2f)(-2.0f), r, (v2f)(1.0f));
}

__device__ __forceinline__ float fast_sigmoid(float v) {
    return FAST_RCP(1.0f + FAST_EXP2(-v * LOG2E));
}

#define ROWS 4

// R7 + ONE change: each thread processes ROWS rows sequentially (block covers
// a contiguous 256*ROWS chunk; lanes stay coalesced within each iteration).
// Amortizes prologue + LDS stage + barrier over 4 rows, and the next row's
// x/S1 loads are issued before the current row's compute -> HBM latency
// (~900 cyc) hides under ~1300 cyc of compute instead of stalling each thread
// once per row. Register state stays 1-row-sized (sequential reuse, not the
// R2-style parallel duplication that halved occupancy).
__global__ __launch_bounds__(256) void subsurf_kernel(
    const float* __restrict__ x, const float* __restrict__ S1,
    const float* __restrict__ W1, const float* __restrict__ b1,
    const float* __restrict__ W2, const float* __restrict__ b2,
    const float* __restrict__ W3, const float* __restrict__ b3,
    float* __restrict__ out, int n)
{
    // Layout: W1[0..72) b1[72..90) W2[90..198) b2[198..216) W3[216..234) b3[234..237)
    __shared__ __align__(16) float w[240];
    int t = threadIdx.x;
    if (t < 72)       w[t] = W1[t];
    else if (t < 90)  w[t] = b1[t - 72];
    else if (t < 198) w[t] = W2[t - 90];
    else if (t < 216) w[t] = b2[t - 198];
    else if (t < 234) w[t] = W3[t - 216];
    else if (t < 237) w[t] = b3[t - 234];
    __syncthreads();

    const v2f* W1p = (const v2f*)(w + 0);    // [(k*4+d)*3 + jp]
    const v2f* b1p = (const v2f*)(w + 72);   // [k*3 + jp]
    const v2f* W2p = (const v2f*)(w + 90);   // [(k*6+ww)*3 + jp]
    const v2f* b2p = (const v2f*)(w + 198);  // [k*3 + jp]
    const float* W3s = w + 216;              // [k*6 + v]
    const float* b3s = w + 234;              // [k]

    // Bit-match numpy f32 constant arithmetic for lows / (highs - lows).
    const float lows[3]   = {100.0f, 0.01f, 0.01f};
    const float ranges[3] = {500.0f - 100.0f, 100.0f - 0.01f, 10.0f - 0.01f};

    int base = blockIdx.x * (256 * ROWS) + t;

    // Prefetch row 0 (clamped index keeps loads in-bounds; stores are guarded).
    int i_cur = base < n ? base : (n - 1);
    float4 xv = ((const float4*)x)[i_cur];
    float s1 = S1[i_cur];

    #pragma unroll
    for (int j = 0; j < ROWS; ++j) {
        int i = base + j * 256;
        // Issue next row's loads before this row's compute (latency hiding).
        float4 xv_n;
        float s1_n = 0.0f;
        if (j + 1 < ROWS) {
            int i_next = (i + 256) < n ? (i + 256) : (n > 0 ? n - 1 : 0);
            xv_n = ((const float4*)x)[i_next];
            s1_n = S1[i_next];
        }

        float xs[4] = {xv.x, xv.y, xv.z, xv.w};

        float vals[3];
        #pragma unroll
        for (int k = 0; k < 3; ++k) {
            float h1[6];
            #pragma unroll
            for (int jp = 0; jp < 3; ++jp) {
                v2f acc = b1p[k * 3 + jp];
                #pragma unroll
                for (int d = 0; d < 4; ++d)
                    acc = v2fma((v2f)(xs[d]), W1p[(k * 4 + d) * 3 + jp], acc);
                v2f th = fast_tanh2(acc);
                h1[2 * jp]     = th.x;
                h1[2 * jp + 1] = th.y;
            }
            float h2[6];
            #pragma unroll
            for (int jp = 0; jp < 3; ++jp) {
                v2f acc = b2p[k * 3 + jp];
                #pragma unroll
                for (int ww = 0; ww < 6; ++ww)
                    acc = v2fma((v2f)(h1[ww]), W2p[(k * 6 + ww) * 3 + jp], acc);
                v2f th = fast_tanh2(acc);
                h2[2 * jp]     = th.x;
                h2[2 * jp + 1] = th.y;
            }
            // Layer 3: scalar sequential order (bit-matches prior rounds).
            float y = b3s[k];
            #pragma unroll
            for (int v = 0; v < 6; ++v)
                y = fmaf(h2[v], W3s[k * 6 + v], y);
            vals[k] = fmaf(ranges[k], fast_sigmoid(y), lows[k]);
        }

        float S1max = vals[0], ks = vals[1], nexp = vals[2];
        // (S1/S1max)^n in log2 domain: handles S1==0 (log2->-inf, exp2->0).
        float lr = FAST_LOG2(s1) - FAST_LOG2(S1max);
        float flow = ks * FAST_EXP2(nexp * lr);
        flow = fminf(fmaxf(flow, 0.0f), S1max);
        if (i < n) out[i] = flow;

        xv = xv_n;
        s1 = s1_n;
    }
}

extern "C" void kernel_launch(void* const* d_in, const int* in_sizes, int n_in,
                              void* d_out, int out_size, void* d_ws, size_t ws_size,
                              hipStream_t stream) {
    const float* x  = (const float*)d_in[0];
    const float* S1 = (const float*)d_in[1];
    const float* W1 = (const float*)d_in[2];
    const float* b1 = (const float*)d_in[3];
    const float* W2 = (const float*)d_in[4];
    const float* b2 = (const float*)d_in[5];
    const float* W3 = (const float*)d_in[6];
    const float* b3 = (const float*)d_in[7];
    float* out = (float*)d_out;

    int n = out_size;  // N = 2,000,000 rows, one output per row
    int rows_per_block = 256 * ROWS;
    int grid = (n + rows_per_block - 1) / rows_per_block;
    subsurf_kernel<<<grid, 256, 0, stream>>>(x, S1, W1, b1, W2, b2, W3, b3, out, n);
}